// Round 1
// baseline (129.321 us; speedup 1.0000x reference)
//
#include <hip/hip_runtime.h>

#define H 1024
#define W 1024
#define NC 12   // channels
#define ND 8    // depth
#define HG 16
#define WG 16

// One block per (n, y). Grid rows iy0/iy1 staged in LDS as [ys][x][z][c]
// so channels are contiguous -> ds_read_b128 per 4 channels per corner.
__global__ __launch_bounds__(256) void slice_kernel(
    const float* __restrict__ grid,
    const float* __restrict__ guide,
    float* __restrict__ out)
{
    const int y   = blockIdx.x;
    const int n   = blockIdx.y;
    const int tid = threadIdx.x;

    // Per-row y interpolation (block-uniform), mirroring the reference math.
    float yn = -1.0f + 2.0f * (float)y / (float)(H - 1);
    float iy = (yn + 1.0f) * 0.5f * (float)(HG - 1);
    iy = fminf(fmaxf(iy, 0.0f), (float)(HG - 1));
    int   iy0 = (int)floorf(iy);
    int   iy1 = min(iy0 + 1, HG - 1);
    float wy  = iy - (float)iy0;

    // Stage the two needed y-rows of the grid into LDS.
    // LDS layout: [ys(2)][x(16)][z(8)][c(12)]  => 3072 floats = 12 KB
    __shared__ __align__(16) float sg[2 * WG * ND * NC];
    const float* gbase = grid + (size_t)n * NC * ND * HG * WG;
    for (int i = tid; i < 2 * NC * ND * WG; i += 256) {
        int x  = i & (WG - 1);
        int z  = (i >> 4) & (ND - 1);
        int cy = i >> 7;          // ys*NC + c
        int c  = cy % NC;
        int ys = cy / NC;
        int yy = ys ? iy1 : iy0;
        float v = gbase[((c * ND + z) * HG + yy) * WG + x];
        sg[((ys * WG + x) * ND + z) * NC + c] = v;
    }
    __syncthreads();

    const float* gd = guide + ((size_t)n * H + y) * W;
    float*       ob = out + ((size_t)n * NC * H + y) * W;  // + c*H*W + x

    for (int x = tid; x < W; x += 256) {
        // x interpolation
        float xn = -1.0f + 2.0f * (float)x / (float)(W - 1);
        float ix = (xn + 1.0f) * 0.5f * (float)(WG - 1);
        ix = fminf(fmaxf(ix, 0.0f), (float)(WG - 1));
        int   ix0 = (int)floorf(ix);
        int   ix1 = min(ix0 + 1, WG - 1);
        float wx  = ix - (float)ix0;

        // z from guide
        float g  = gd[x];
        float zn = g * 2.0f - 1.0f;
        float iz = (zn + 1.0f) * 0.5f * (float)(ND - 1);
        iz = fminf(fmaxf(iz, 0.0f), (float)(ND - 1));
        int   iz0 = (int)floorf(iz);
        int   iz1 = min(iz0 + 1, ND - 1);
        float wz  = iz - (float)iz0;
        float omz = 1.0f - wz;

        // LDS bases (float indices) for the 4 xy corners
        int b00 = (ix0 * ND) * NC;                 // ys=0, x=ix0
        int b01 = (ix1 * ND) * NC;                 // ys=0, x=ix1
        int b10 = ((WG + ix0) * ND) * NC;          // ys=1, x=ix0
        int b11 = ((WG + ix1) * ND) * NC;          // ys=1, x=ix1
        int oz0 = iz0 * NC;
        int oz1 = iz1 * NC;

        float w00 = (1.0f - wy) * (1.0f - wx);
        float w01 = (1.0f - wy) * wx;
        float w10 = wy * (1.0f - wx);
        float w11 = wy * wx;

        #pragma unroll
        for (int cc = 0; cc < NC; cc += 4) {
            const float4 a00 = *(const float4*)&sg[b00 + oz0 + cc];
            const float4 b00v= *(const float4*)&sg[b00 + oz1 + cc];
            const float4 a01 = *(const float4*)&sg[b01 + oz0 + cc];
            const float4 b01v= *(const float4*)&sg[b01 + oz1 + cc];
            const float4 a10 = *(const float4*)&sg[b10 + oz0 + cc];
            const float4 b10v= *(const float4*)&sg[b10 + oz1 + cc];
            const float4 a11 = *(const float4*)&sg[b11 + oz0 + cc];
            const float4 b11v= *(const float4*)&sg[b11 + oz1 + cc];

            float r0 = (a00.x * omz + b00v.x * wz) * w00
                     + (a01.x * omz + b01v.x * wz) * w01
                     + (a10.x * omz + b10v.x * wz) * w10
                     + (a11.x * omz + b11v.x * wz) * w11;
            float r1 = (a00.y * omz + b00v.y * wz) * w00
                     + (a01.y * omz + b01v.y * wz) * w01
                     + (a10.y * omz + b10v.y * wz) * w10
                     + (a11.y * omz + b11v.y * wz) * w11;
            float r2 = (a00.z * omz + b00v.z * wz) * w00
                     + (a01.z * omz + b01v.z * wz) * w01
                     + (a10.z * omz + b10v.z * wz) * w10
                     + (a11.z * omz + b11v.z * wz) * w11;
            float r3 = (a00.w * omz + b00v.w * wz) * w00
                     + (a01.w * omz + b01v.w * wz) * w01
                     + (a10.w * omz + b10v.w * wz) * w10
                     + (a11.w * omz + b11v.w * wz) * w11;

            ob[(size_t)(cc + 0) * H * W + x] = r0;
            ob[(size_t)(cc + 1) * H * W + x] = r1;
            ob[(size_t)(cc + 2) * H * W + x] = r2;
            ob[(size_t)(cc + 3) * H * W + x] = r3;
        }
    }
}

extern "C" void kernel_launch(void* const* d_in, const int* in_sizes, int n_in,
                              void* d_out, int out_size, void* d_ws, size_t ws_size,
                              hipStream_t stream) {
    const float* grid  = (const float*)d_in[0];
    const float* guide = (const float*)d_in[1];
    float* out = (float*)d_out;

    dim3 grd(H, 2);   // (y, n)
    dim3 blk(256);
    slice_kernel<<<grd, blk, 0, stream>>>(grid, guide, out);
}

// Round 2
// 122.014 us; speedup vs baseline: 1.0599x; 1.0599x over previous
//
#include <hip/hip_runtime.h>

#define H 1024
#define W 1024
#define NC 12   // channels
#define ND 8    // depth
#define HG 16
#define WG 16

// One block per (n, y). wy is block-uniform, so the y-interpolation is folded
// into the LDS staging step: sg[x][z][c] = row(iy0)*(1-wy) + row(iy1)*wy.
// Main loop is then a bilinear (x,z) gather: 12 ds_read_b128 per pixel.
// Each thread produces 4 consecutive pixels and writes float4 per channel.
__global__ __launch_bounds__(256) void slice_kernel(
    const float* __restrict__ grid,
    const float* __restrict__ guide,
    float* __restrict__ out)
{
    const int y   = blockIdx.x;
    const int n   = blockIdx.y;
    const int tid = threadIdx.x;

    // Per-row y interpolation (block-uniform), mirroring the reference math.
    float yn = -1.0f + 2.0f * (float)y / (float)(H - 1);
    float iy = (yn + 1.0f) * 0.5f * (float)(HG - 1);
    iy = fminf(fmaxf(iy, 0.0f), (float)(HG - 1));
    int   iy0 = (int)floorf(iy);
    int   iy1 = min(iy0 + 1, HG - 1);
    float wy  = iy - (float)iy0;

    // LDS: y-interpolated grid row, layout [x(16)][z(8)][c(12)] = 1536 f = 6 KB
    __shared__ __align__(16) float sg[WG * ND * NC];
    const float* gbase = grid + (size_t)n * NC * ND * HG * WG;
    for (int i = tid; i < WG * ND * NC; i += 256) {
        int x  = i & (WG - 1);
        int zc = i >> 4;
        int z  = zc & (ND - 1);
        int c  = zc >> 3;
        const float* gp = gbase + ((c * ND + z) * HG) * WG + x;
        float r0 = gp[iy0 * WG];
        float r1 = gp[iy1 * WG];
        sg[(x * ND + z) * NC + c] = r0 + (r1 - r0) * wy;
    }
    __syncthreads();

    const int xb = tid * 4;                       // 4 consecutive pixels/thread
    const float* gd = guide + ((size_t)n * H + y) * W;
    float*       ob = out + ((size_t)n * NC * H + y) * W;  // + c*H*W + x

    const float4 g4 = *(const float4*)&gd[xb];
    const float gz[4] = {g4.x, g4.y, g4.z, g4.w};

    float res[NC][4];

    #pragma unroll
    for (int p = 0; p < 4; ++p) {
        const int x = xb + p;
        // x interpolation
        float xn = -1.0f + 2.0f * (float)x / (float)(W - 1);
        float ix = (xn + 1.0f) * 0.5f * (float)(WG - 1);
        ix = fminf(fmaxf(ix, 0.0f), (float)(WG - 1));
        int   ix0 = (int)floorf(ix);
        int   ix1 = min(ix0 + 1, WG - 1);
        float wx  = ix - (float)ix0;

        // z from guide
        float zn = gz[p] * 2.0f - 1.0f;
        float iz = (zn + 1.0f) * 0.5f * (float)(ND - 1);
        iz = fminf(fmaxf(iz, 0.0f), (float)(ND - 1));
        int   iz0 = (int)floorf(iz);
        int   iz1 = min(iz0 + 1, ND - 1);
        float wz  = iz - (float)iz0;

        const int B0 = ix0 * (ND * NC);
        const int B1 = ix1 * (ND * NC);
        const int Z0 = iz0 * NC;
        const int Z1 = iz1 * NC;

        #pragma unroll
        for (int cc = 0; cc < NC; cc += 4) {
            const float4 a0 = *(const float4*)&sg[B0 + Z0 + cc];
            const float4 a1 = *(const float4*)&sg[B0 + Z1 + cc];
            const float4 b0 = *(const float4*)&sg[B1 + Z0 + cc];
            const float4 b1 = *(const float4*)&sg[B1 + Z1 + cc];

            // z-lerp then x-lerp (lerp form: a + (b-a)*t)
            float za, zb;
            za = a0.x + (a1.x - a0.x) * wz;
            zb = b0.x + (b1.x - b0.x) * wz;
            res[cc + 0][p] = za + (zb - za) * wx;

            za = a0.y + (a1.y - a0.y) * wz;
            zb = b0.y + (b1.y - b0.y) * wz;
            res[cc + 1][p] = za + (zb - za) * wx;

            za = a0.z + (a1.z - a0.z) * wz;
            zb = b0.z + (b1.z - b0.z) * wz;
            res[cc + 2][p] = za + (zb - za) * wx;

            za = a0.w + (a1.w - a0.w) * wz;
            zb = b0.w + (b1.w - b0.w) * wz;
            res[cc + 3][p] = za + (zb - za) * wx;
        }
    }

    #pragma unroll
    for (int c = 0; c < NC; ++c) {
        float4 v = make_float4(res[c][0], res[c][1], res[c][2], res[c][3]);
        *(float4*)&ob[(size_t)c * H * W + xb] = v;
    }
}

extern "C" void kernel_launch(void* const* d_in, const int* in_sizes, int n_in,
                              void* d_out, int out_size, void* d_ws, size_t ws_size,
                              hipStream_t stream) {
    const float* grid  = (const float*)d_in[0];
    const float* guide = (const float*)d_in[1];
    float* out = (float*)d_out;

    dim3 grd(H, 2);   // (y, n)
    dim3 blk(256);
    slice_kernel<<<grd, blk, 0, stream>>>(grid, guide, out);
}